// Round 17
// baseline (123.277 us; speedup 1.0000x reference)
//
#include <hip/hip_runtime.h>
#include <hip/hip_bf16.h>

#define DEV __device__ __forceinline__

typedef short bf16x8 __attribute__((ext_vector_type(8)));
typedef float f32x4  __attribute__((ext_vector_type(4)));

#define Bc 2
#define Sc 2048
#define Dc 1024
#define Hc 16
// DEPTH = 64, M = B*S = 4096

// ---- workspace layout (bytes) ----
#define OFF_XB    0u           // batch bf16        [4096][1024]   8388608
#define OFF_WQKVT 8388608u     // Wqkv^T bf16       [3072][1024]   6291456
#define OFF_WOT   14680064u    // Wo^T bf16         [1024][1024]   2097152
#define OFF_Q     16777216u    // Q bf16 (B,H,S,64), pre-scaled    8388608
#define OFF_K     25165824u    // K bf16 (B,H,S,64)                8388608
#define OFF_VT    33554432u    // V^T bf16 (B,H,64,S) KEY-PERMUTED 8388608
#define OFF_XA    41943040u    // attn out bf16 [4096][1024]       8388608
#define OFF_BIASC 50331648u    // f32 [3072]                         12288
#define OFF_LENS  50343936u    // int [B]
// V (B,H,S,64) bf16 scratch lives in d_out[0..8MB) — rewritten every call,
// consumed by vtrans, then fully overwritten by gemm_out (deterministic).

DEV short f2bf(float f) {
    __hip_bfloat16 h = __float2bfloat16(f);
    union { __hip_bfloat16 h; short s; } u; u.h = h; return u.s;
}

DEV int cvtpk(float lo, float hi_) {
    int r;
    asm("v_cvt_pk_bf16_f32 %0, %1, %2" : "=v"(r) : "v"(lo), "v"(hi_));
    return r;
}

DEV float vexp2(float x) {
    float r;
    asm("v_exp_f32 %0, %1" : "=v"(r) : "v"(x));   // hardware 2^x, ~1 ULP
    return r;
}

DEV void gload16(const void* g, void* l) {
    __builtin_amdgcn_global_load_lds((const __attribute__((address_space(1))) void*)g,
                                     (__attribute__((address_space(3))) void*)l, 16, 0, 0);
}

union I4BF { int i[4]; bf16x8 v; };

// ---------------- fused prep: cast + 4x weight transpose + bias/mask ----------------
__global__ __launch_bounds__(256) void prep_all_kernel(
    const float* __restrict__ batch,
    const float* __restrict__ Wq, const float* __restrict__ Wk,
    const float* __restrict__ Wv, const float* __restrict__ Wo,
    const float* __restrict__ bq, const float* __restrict__ bk, const float* __restrict__ bv,
    const unsigned char* __restrict__ mask,
    short* __restrict__ XB, short* __restrict__ WQKVT, short* __restrict__ WOT,
    float* __restrict__ biasc, int* __restrict__ lens)
{
    __shared__ float tsm[32][33];
    __shared__ int cnt;
    int blk = blockIdx.x, t = threadIdx.x;

    if (blk < 4096) {                       // ---- cast batch f32 -> bf16 (float4/lane)
        int i = blk * 256 + t;
        float4 v = ((const float4*)batch)[i];
        short4 o;
        o.x = f2bf(v.x); o.y = f2bf(v.y); o.z = f2bf(v.z); o.w = f2bf(v.w);
        ((short4*)XB)[i] = o;
        return;
    }
    if (blk < 8192) {                       // ---- weight transpose-cast (4 x 1024 tiles)
        int w = blk - 4096, z = w >> 10, tile = w & 1023;
        const float* src; short* dst;
        if (z == 0)      { src = Wq; dst = WQKVT; }
        else if (z == 1) { src = Wk; dst = WQKVT + 1024 * 1024; }
        else if (z == 2) { src = Wv; dst = WQKVT + 2 * 1024 * 1024; }
        else             { src = Wo; dst = WOT; }
        int tx = t & 31, ty = t >> 5;       // 32 x 8
        int r0 = (tile >> 5) * 32, c0 = (tile & 31) * 32;
#pragma unroll
        for (int i = 0; i < 4; i++)
            tsm[ty + i * 8][tx] = src[(size_t)(r0 + ty + i * 8) * Dc + c0 + tx];
        __syncthreads();
#pragma unroll
        for (int i = 0; i < 4; i++)
            dst[(size_t)(c0 + ty + i * 8) * Dc + r0 + tx] = f2bf(tsm[tx][ty + i * 8]);
        return;
    }
    if (blk == 8192) {                      // ---- bias concat
        for (int i = t; i < Dc; i += 256) {
            biasc[i] = bq[i]; biasc[Dc + i] = bk[i]; biasc[2 * Dc + i] = bv[i];
        }
        return;
    }
    {                                       // ---- mask lengths (blocks 8193, 8194)
        int b = blk - 8193;
        bool is_i32 = (mask[1] == 0);
        if (t == 0) cnt = 0;
        __syncthreads();
        int local = 0;
        for (int s = t; s < Sc; s += 256) {
            bool v = is_i32 ? (((const int*)mask)[b * Sc + s] != 0) : (mask[b * Sc + s] != 0);
            local += v ? 1 : 0;
        }
        atomicAdd(&cnt, local);
        __syncthreads();
        if (t == 0) lens[b] = cnt;
    }
}

// V (B,H,S,64) -> V^T (B,H,64,S) with per-32-key permutation:
// position p = g*8+j  holds key = (j<4) ? 4g+j : 16+4g+(j-4)   (g=0..3, j=0..7)
__global__ __launch_bounds__(256) void vtrans_kernel(const short* __restrict__ V,
                                                     short* __restrict__ VT,
                                                     const int* __restrict__ lens) {
    __shared__ short t[64][65];
    int tid = threadIdx.x;
    int bh = blockIdx.y, s0 = blockIdx.x * 64;
    int b = bh >> 4;
    int kv_end = ((lens[b] + 63) >> 6) << 6;
    if (s0 >= kv_end) return;
    int rr = tid >> 2, c4 = (tid & 3) * 16;
    const short* vrow = V + ((size_t)bh * Sc + s0 + rr) * 64 + c4;
    *(bf16x8*)&t[rr][c4]     = *(const bf16x8*)(vrow);
    *(bf16x8*)&t[rr][c4 + 8] = *(const bf16x8*)(vrow + 8);
    __syncthreads();
    int q2 = tid & 3;
    int gidx = q2 >> 1, half = q2 & 1;
    int base = gidx * 32, off = half * 8;
    bf16x8 a, b2;
#pragma unroll
    for (int i = 0; i < 4; i++) {
        a[i]      = t[base + off + i][rr];
        a[4 + i]  = t[base + 16 + off + i][rr];
        b2[i]     = t[base + off + 4 + i][rr];
        b2[4 + i] = t[base + 16 + off + 4 + i][rr];
    }
    short* orow = VT + ((size_t)bh * 64 + rr) * Sc + s0 + base + half * 16;
    *(bf16x8*)(orow)     = a;
    *(bf16x8*)(orow + 8) = b2;
}

// ---------------- 128x128 bf16 MFMA GEMM: QKV projection, BK=64 + XOR swizzle -------
// [128][64] staging tiles (128B rows), attn-proven pattern: linear LDS dest +
// pre-swizzled global source + XOR on fragment reads (conflict-free), barriers halved.
__global__ __launch_bounds__(256) void gemm_qkv_kernel(
    const short* __restrict__ A, const short* __restrict__ BT, const float* __restrict__ bias,
    short* __restrict__ Qp, short* __restrict__ Kp, short* __restrict__ Vp,
    const int* __restrict__ lens)
{
    __shared__ short As[128 * 64];
    __shared__ short Bs[128 * 64];
    int tid = threadIdx.x, lane = tid & 63, wave = tid >> 6;
    int l15 = lane & 15, lhi = lane >> 4;
    int bm = blockIdx.x, bn = blockIdx.y;

    if (bn >= 8) {                          // K or V columns: skip fully-masked row blocks
        int brow = bm >> 4;
        int s_lo = (bm & 15) * 128;
        int kv_end = ((lens[brow] + 63) >> 6) << 6;
        if (s_lo >= kv_end) return;
    }

    int wm = wave >> 1, wn = wave & 1;
    int rsw = (l15 & 7) << 4;

    const f32x4 fzero = {0.f, 0.f, 0.f, 0.f};
    f32x4 acc[4][4];
#pragma unroll
    for (int i = 0; i < 4; i++)
#pragma unroll
        for (int j = 0; j < 4; j++) acc[i][j] = fzero;

    const char* Ab = (const char*)A;
    const char* Bb = (const char*)BT;

    for (int k0 = 0; k0 < 1024; k0 += 64) {
#pragma unroll
        for (int i = 0; i < 4; i++) {
            int o = i * 4096 + tid * 16;
            int row = o >> 7, cb = o & 127;
            int scb = cb ^ ((row & 7) << 4);
            gload16(Ab + ((size_t)(bm * 128 + row) * 1024 + k0) * 2 + scb, (char*)As + o);
            gload16(Bb + ((size_t)(bn * 128 + row) * 1024 + k0) * 2 + scb, (char*)Bs + o);
        }
        __syncthreads();
#pragma unroll
        for (int kk = 0; kk < 2; kk++) {
            bf16x8 af[4], bfv[4];
#pragma unroll
            for (int i = 0; i < 4; i++) {
                int rowa = wm * 64 + i * 16 + l15;     // rowa&7 == l15&7
                int rowb = wn * 64 + i * 16 + l15;
                af[i]  = *(const bf16x8*)((char*)As + rowa * 128 +
                                          ((kk * 64 + lhi * 16) ^ rsw));
                bfv[i] = *(const bf16x8*)((char*)Bs + rowb * 128 +
                                          ((kk * 64 + lhi * 16) ^ rsw));
            }
#pragma unroll
            for (int i = 0; i < 4; i++)
#pragma unroll
                for (int j = 0; j < 4; j++)
                    acc[i][j] = __builtin_amdgcn_mfma_f32_16x16x32_bf16(af[i], bfv[j], acc[i][j], 0, 0, 0);
        }
        __syncthreads();
    }

#pragma unroll
    for (int i = 0; i < 4; i++)
#pragma unroll
        for (int j = 0; j < 4; j++) {
            int c = bn * 128 + wn * 64 + j * 16 + l15;
            float bc = bias[c];
            int rb = bm * 128 + wm * 64 + i * 16 + 4 * lhi;
#pragma unroll
            for (int reg = 0; reg < 4; reg++) {
                int r = rb + reg;
                float v = acc[i][j][reg] + bc;
                int which = c >> 10, cc = c & 1023, h = cc >> 6, d = cc & 63;
                int b = r >> 11, s = r & 2047;
                int bh = b * Hc + h;
                if (which == 0) v *= 0.18033688f;   // fold 1/8 * log2(e) into Q
                short sv = f2bf(v);
                size_t idx = ((size_t)bh * Sc + s) * 64 + d;
                if (which == 0)      Qp[idx] = sv;
                else if (which == 1) Kp[idx] = sv;
                else                 Vp[idx] = sv;
            }
        }
}

// ---------------- 128x64 bf16 MFMA GEMM: output projection, BK=64 + swizzle ---------
__global__ __launch_bounds__(256) void gemm_out_kernel(
    const short* __restrict__ A, const short* __restrict__ BT, const float* __restrict__ bias,
    float* __restrict__ outF)
{
    __shared__ short As[128 * 64];
    __shared__ short Bs[64 * 64];
    int tid = threadIdx.x, lane = tid & 63, wave = tid >> 6;
    int l15 = lane & 15, lhi = lane >> 4;
    int bm = blockIdx.x, bn = blockIdx.y;
    int rsw = (l15 & 7) << 4;

    const f32x4 fzero = {0.f, 0.f, 0.f, 0.f};
    f32x4 acc[2][4];
#pragma unroll
    for (int i = 0; i < 2; i++)
#pragma unroll
        for (int j = 0; j < 4; j++) acc[i][j] = fzero;

    const char* Ab = (const char*)A;
    const char* Bb = (const char*)BT;

    for (int k0 = 0; k0 < 1024; k0 += 64) {
#pragma unroll
        for (int i = 0; i < 4; i++) {
            int o = i * 4096 + tid * 16;
            int row = o >> 7, cb = o & 127;
            int scb = cb ^ ((row & 7) << 4);
            gload16(Ab + ((size_t)(bm * 128 + row) * 1024 + k0) * 2 + scb, (char*)As + o);
        }
#pragma unroll
        for (int i = 0; i < 2; i++) {
            int o = i * 4096 + tid * 16;
            int row = o >> 7, cb = o & 127;
            int scb = cb ^ ((row & 7) << 4);
            gload16(Bb + ((size_t)(bn * 64 + row) * 1024 + k0) * 2 + scb, (char*)Bs + o);
        }
        __syncthreads();
#pragma unroll
        for (int kk = 0; kk < 2; kk++) {
            bf16x8 af[2], bfv[4];
#pragma unroll
            for (int i = 0; i < 2; i++) {
                int rowa = wave * 32 + i * 16 + l15;
                af[i] = *(const bf16x8*)((char*)As + rowa * 128 +
                                         ((kk * 64 + lhi * 16) ^ rsw));
            }
#pragma unroll
            for (int j = 0; j < 4; j++) {
                int rowb = j * 16 + l15;
                bfv[j] = *(const bf16x8*)((char*)Bs + rowb * 128 +
                                          ((kk * 64 + lhi * 16) ^ rsw));
            }
#pragma unroll
            for (int i = 0; i < 2; i++)
#pragma unroll
                for (int j = 0; j < 4; j++)
                    acc[i][j] = __builtin_amdgcn_mfma_f32_16x16x32_bf16(af[i], bfv[j], acc[i][j], 0, 0, 0);
        }
        __syncthreads();
    }

#pragma unroll
    for (int i = 0; i < 2; i++)
#pragma unroll
        for (int j = 0; j < 4; j++) {
            int c = bn * 64 + j * 16 + l15;
            float bc = bias[c];
            int rb = bm * 128 + wave * 32 + i * 16 + 4 * lhi;
#pragma unroll
            for (int reg = 0; reg < 4; reg++)
                outF[(size_t)(rb + reg) * Dc + c] = acc[i][j][reg] + bc;
        }
}

// ------- flash attention: 16x16x32 swapped-operand (r16) + l-via-MFMA ones trick ----
// 4-wave blocks (64 q-rows), grid 1024, batch-balanced bijective XCD swizzle.
// l is accumulated by mfma(ones, P) — permutation-invariant sum over keys, so every
// lane ends holding l for q=lane&15 (no VALU tree-sum, no epilogue shuffles).
__global__ __launch_bounds__(256) void attn_kernel(
    const short* __restrict__ Qp, const short* __restrict__ Kp, const short* __restrict__ VTp,
    const int* __restrict__ lens, short* __restrict__ Xout)
{
    int tid = threadIdx.x, lane = tid & 63, wave = tid >> 6;   // wave 0..3
    int l15 = lane & 15, g4 = lane >> 4;                       // g4 0..3

    int orig = blockIdx.x;                  // 1024 blocks, 1024 % 8 == 0 -> bijective
    int xcd = orig & 7, idx = orig >> 3;
    int j = idx & 3, bx = idx >> 2;
    int bh = ((j >> 1) << 4) + xcd * 2 + (j & 1);
    int b = bh >> 4, h = bh & 15;
    int q0 = bx * 64 + wave * 16;

    __shared__ short Kt[2][64 * 64];
    __shared__ short Vt[2][64 * 64];

    const short* Qb  = Qp + (size_t)bh * Sc * 64;
    const char*  Kb  = (const char*)(Kp + (size_t)bh * Sc * 64);
    const char*  VTb = (const char*)(VTp + (size_t)bh * 64 * Sc);

    bf16x8 qf0 = *(const bf16x8*)(Qb + (size_t)(q0 + l15) * 64 + g4 * 8);
    bf16x8 qf1 = *(const bf16x8*)(Qb + (size_t)(q0 + l15) * 64 + 32 + g4 * 8);

    bf16x8 onesv;
#pragma unroll
    for (int i = 0; i < 8; i++) onesv[i] = (short)0x3F80;   // bf16 1.0

    const f32x4 FZ = {0.f, 0.f, 0.f, 0.f};
    f32x4 xacc[4], lacc = FZ;
#pragma unroll
    for (int dt = 0; dt < 4; dt++) xacc[dt] = FZ;

    int len = lens[b];
    int nt = (len + 63) >> 6;
    int rsw = (l15 & 7) << 4;
    int g16 = g4 * 16;

#define STAGE(bufi, kt_)                                                              \
    {                                                                                 \
        int k0_ = (kt_) * 64;                                                         \
        _Pragma("unroll")                                                             \
        for (int i = 0; i < 2; i++) {                                                 \
            int o = i * 4096 + tid * 16;                                              \
            int row = o >> 7, cb = o & 127;                                           \
            int scb = cb ^ ((row & 7) << 4);                                          \
            gload16(Kb + (size_t)(k0_ + row) * 128 + scb,                             \
                    (char*)&Kt[bufi][0] + o);                                         \
            gload16(VTb + (size_t)row * (Sc * 2) + (size_t)k0_ * 2 + scb,             \
                    (char*)&Vt[bufi][0] + o);                                         \
        }                                                                             \
    }

#define DOTILE(BUFI, KT)                                                              \
    {                                                                                 \
        const char* Kc = (const char*)&Kt[BUFI][0];                                   \
        const char* Vc = (const char*)&Vt[BUFI][0];                                   \
        f32x4 s[4];                                                                   \
        __builtin_amdgcn_s_setprio(1);                                                \
        _Pragma("unroll")                                                             \
        for (int k16 = 0; k16 < 4; k16++) {                                           \
            const char* kr = Kc + (k16 * 16 + l15) * 128;                             \
            bf16x8 kf0 = *(const bf16x8*)(kr + (g16 ^ rsw));                          \
            bf16x8 kf1 = *(const bf16x8*)(kr + ((64 + g16) ^ rsw));                   \
            s[k16] = __builtin_amdgcn_mfma_f32_16x16x32_bf16(kf0, qf0, FZ, 0, 0, 0);  \
            s[k16] = __builtin_amdgcn_mfma_f32_16x16x32_bf16(kf1, qf1, s[k16], 0, 0, 0);\
        }                                                                             \
        __builtin_amdgcn_s_setprio(0);                                                \
        if ((KT) == nt - 1) {                                                         \
            int rem = len - (KT) * 64;                                                \
            if (rem < 64) {                                                           \
                _Pragma("unroll")                                                     \
                for (int k16 = 0; k16 < 4; k16++)                                     \
                    _Pragma("unroll")                                                 \
                    for (int r = 0; r < 4; r++) {                                     \
                        int key0 = k16 * 16 + 4 * g4 + r;                             \
                        if (key0 >= rem) s[k16][r] = -3.0e38f;                        \
                    }                                                                 \
            }                                                                         \
        }                                                                             \
        _Pragma("unroll")                                                             \
        for (int k16 = 0; k16 < 4; k16++)                                             \
            _Pragma("unroll")                                                         \
            for (int r = 0; r < 4; r++) s[k16][r] = vexp2(s[k16][r]);                 \
        I4BF p0, p1;                                                                  \
        p0.i[0] = cvtpk(s[0][0], s[0][1]); p0.i[1] = cvtpk(s[0][2], s[0][3]);         \
        p0.i[2] = cvtpk(s[1][0], s[1][1]); p0.i[3] = cvtpk(s[1][2], s[1][3]);         \
        p1.i[0] = cvtpk(s[2][0], s[2][1]); p1.i[1] = cvtpk(s[2][2], s[2][3]);         \
        p1.i[2] = cvtpk(s[3][0], s[3][1]); p1.i[3] = cvtpk(s[3][2], s[3][3]);         \
        __builtin_amdgcn_s_setprio(1);                                                \
        lacc = __builtin_amdgcn_mfma_f32_16x16x32_bf16(onesv, p0.v, lacc, 0, 0, 0);   \
        lacc = __builtin_amdgcn_mfma_f32_16x16x32_bf16(onesv, p1.v, lacc, 0, 0, 0);   \
        _Pragma("unroll")                                                             \
        for (int dt = 0; dt < 4; dt++) {                                              \
            const char* vr = Vc + (dt * 16 + l15) * 128;                              \
            bf16x8 v0 = *(const bf16x8*)(vr + (g16 ^ rsw));                           \
            bf16x8 v1 = *(const bf16x8*)(vr + ((64 + g16) ^ rsw));                    \
            xacc[dt] = __builtin_amdgcn_mfma_f32_16x16x32_bf16(v0, p0.v, xacc[dt], 0, 0, 0);\
            xacc[dt] = __builtin_amdgcn_mfma_f32_16x16x32_bf16(v1, p1.v, xacc[dt], 0, 0, 0);\
        }                                                                             \
        __builtin_amdgcn_s_setprio(0);                                                \
    }

    STAGE(0, 0);
    __syncthreads();

    int kt = 0;
    while (kt + 2 <= nt) {
        if (kt + 1 < nt) STAGE(1, kt + 1);
        DOTILE(0, kt);
        __syncthreads();
        if (kt + 2 < nt) STAGE(0, kt + 2);
        DOTILE(1, kt + 1);
        __syncthreads();
        kt += 2;
    }
    if (kt < nt) DOTILE(0, kt);

    // epilogue: every lane already holds l for q=l15 in lacc (all rows identical)
    float rl = 1.0f / lacc[0];
    short* orow = Xout + (size_t)(b * Sc + q0 + l15) * Dc + h * 64;
#pragma unroll
    for (int dt = 0; dt < 4; dt++) {
        short4 o;
        o.x = f2bf(xacc[dt][0] * rl);
        o.y = f2bf(xacc[dt][1] * rl);
        o.z = f2bf(xacc[dt][2] * rl);
        o.w = f2bf(xacc[dt][3] * rl);
        *(short4*)(orow + dt * 16 + 4 * g4) = o;
    }
}

// ---------------- launch ----------------

extern "C" void kernel_launch(void* const* d_in, const int* in_sizes, int n_in,
                              void* d_out, int out_size, void* d_ws, size_t ws_size,
                              hipStream_t stream) {
    const float* batch = (const float*)d_in[0];
    const unsigned char* mask = (const unsigned char*)d_in[1];
    const float* Wq = (const float*)d_in[2];
    const float* bq = (const float*)d_in[3];
    const float* Wk = (const float*)d_in[4];
    const float* bk = (const float*)d_in[5];
    const float* Wv = (const float*)d_in[6];
    const float* bv = (const float*)d_in[7];
    const float* Wo = (const float*)d_in[8];
    const float* bo = (const float*)d_in[9];

    char* ws = (char*)d_ws;
    short* XB    = (short*)(ws + OFF_XB);
    short* WQKVT = (short*)(ws + OFF_WQKVT);
    short* WOT   = (short*)(ws + OFF_WOT);
    short* Qb    = (short*)(ws + OFF_Q);
    short* Kb    = (short*)(ws + OFF_K);
    short* VTb   = (short*)(ws + OFF_VT);
    short* XAb   = (short*)(ws + OFF_XA);
    float* BIASC = (float*)(ws + OFF_BIASC);
    int*   LENS  = (int*)(ws + OFF_LENS);
    short* Vscr  = (short*)d_out;   // V (B,H,S,64) scratch in d_out (overwritten by gemm_out)

    prep_all_kernel<<<8195, 256, 0, stream>>>(batch, Wq, Wk, Wv, Wo, bq, bk, bv, mask,
                                              XB, WQKVT, WOT, BIASC, LENS);
    gemm_qkv_kernel<<<dim3(32, 24), 256, 0, stream>>>(XB, WQKVT, BIASC, Qb, Kb, Vscr, LENS);
    vtrans_kernel<<<dim3(32, 32), 256, 0, stream>>>(Vscr, VTb, LENS);
    attn_kernel<<<1024, 256, 0, stream>>>(Qb, Kb, VTb, LENS, XAb);
    gemm_out_kernel<<<dim3(32, 16), 256, 0, stream>>>(XAb, WOT, bo, (float*)d_out);
}

// Round 18
// 118.406 us; speedup vs baseline: 1.0411x; 1.0411x over previous
//
#include <hip/hip_runtime.h>
#include <hip/hip_bf16.h>

#define DEV __device__ __forceinline__

typedef short bf16x8 __attribute__((ext_vector_type(8)));
typedef float f32x4  __attribute__((ext_vector_type(4)));

#define Bc 2
#define Sc 2048
#define Dc 1024
#define Hc 16
// DEPTH = 64, M = B*S = 4096

// ---- workspace layout (bytes) ----
#define OFF_XB    0u           // batch bf16        [4096][1024]   8388608
#define OFF_WQKVT 8388608u     // Wqkv^T bf16       [3072][1024]   6291456
#define OFF_WOT   14680064u    // Wo^T bf16         [1024][1024]   2097152
#define OFF_Q     16777216u    // Q bf16 (B,H,S,64), pre-scaled    8388608
#define OFF_K     25165824u    // K bf16 (B,H,S,64)                8388608
#define OFF_VT    33554432u    // V^T bf16 (B,H,64,S) KEY-PERMUTED 8388608
#define OFF_XA    41943040u    // attn out bf16 [4096][1024]       8388608
#define OFF_BIASC 50331648u    // f32 [3072]                         12288
#define OFF_LENS  50343936u    // int [B]
// V (B,H,S,64) bf16 scratch lives in d_out[0..8MB) — rewritten every call,
// consumed by vtrans, then fully overwritten by gemm_out (deterministic).

DEV short f2bf(float f) {
    __hip_bfloat16 h = __float2bfloat16(f);
    union { __hip_bfloat16 h; short s; } u; u.h = h; return u.s;
}

DEV int cvtpk(float lo, float hi_) {
    int r;
    asm("v_cvt_pk_bf16_f32 %0, %1, %2" : "=v"(r) : "v"(lo), "v"(hi_));
    return r;
}

DEV float vexp2(float x) {
    float r;
    asm("v_exp_f32 %0, %1" : "=v"(r) : "v"(x));   // hardware 2^x, ~1 ULP
    return r;
}

DEV void gload16(const void* g, void* l) {
    __builtin_amdgcn_global_load_lds((const __attribute__((address_space(1))) void*)g,
                                     (__attribute__((address_space(3))) void*)l, 16, 0, 0);
}

union I4BF { int i[4]; bf16x8 v; };

// ---------------- fused prep: cast + 4x weight transpose + bias/mask ----------------
__global__ __launch_bounds__(256) void prep_all_kernel(
    const float* __restrict__ batch,
    const float* __restrict__ Wq, const float* __restrict__ Wk,
    const float* __restrict__ Wv, const float* __restrict__ Wo,
    const float* __restrict__ bq, const float* __restrict__ bk, const float* __restrict__ bv,
    const unsigned char* __restrict__ mask,
    short* __restrict__ XB, short* __restrict__ WQKVT, short* __restrict__ WOT,
    float* __restrict__ biasc, int* __restrict__ lens)
{
    __shared__ float tsm[32][33];
    __shared__ int cnt;
    int blk = blockIdx.x, t = threadIdx.x;

    if (blk < 4096) {                       // ---- cast batch f32 -> bf16 (float4/lane)
        int i = blk * 256 + t;
        float4 v = ((const float4*)batch)[i];
        short4 o;
        o.x = f2bf(v.x); o.y = f2bf(v.y); o.z = f2bf(v.z); o.w = f2bf(v.w);
        ((short4*)XB)[i] = o;
        return;
    }
    if (blk < 8192) {                       // ---- weight transpose-cast (4 x 1024 tiles)
        int w = blk - 4096, z = w >> 10, tile = w & 1023;
        const float* src; short* dst;
        if (z == 0)      { src = Wq; dst = WQKVT; }
        else if (z == 1) { src = Wk; dst = WQKVT + 1024 * 1024; }
        else if (z == 2) { src = Wv; dst = WQKVT + 2 * 1024 * 1024; }
        else             { src = Wo; dst = WOT; }
        int tx = t & 31, ty = t >> 5;       // 32 x 8
        int r0 = (tile >> 5) * 32, c0 = (tile & 31) * 32;
#pragma unroll
        for (int i = 0; i < 4; i++)
            tsm[ty + i * 8][tx] = src[(size_t)(r0 + ty + i * 8) * Dc + c0 + tx];
        __syncthreads();
#pragma unroll
        for (int i = 0; i < 4; i++)
            dst[(size_t)(c0 + ty + i * 8) * Dc + r0 + tx] = f2bf(tsm[tx][ty + i * 8]);
        return;
    }
    if (blk == 8192) {                      // ---- bias concat
        for (int i = t; i < Dc; i += 256) {
            biasc[i] = bq[i]; biasc[Dc + i] = bk[i]; biasc[2 * Dc + i] = bv[i];
        }
        return;
    }
    {                                       // ---- mask lengths (blocks 8193, 8194)
        int b = blk - 8193;
        bool is_i32 = (mask[1] == 0);
        if (t == 0) cnt = 0;
        __syncthreads();
        int local = 0;
        for (int s = t; s < Sc; s += 256) {
            bool v = is_i32 ? (((const int*)mask)[b * Sc + s] != 0) : (mask[b * Sc + s] != 0);
            local += v ? 1 : 0;
        }
        atomicAdd(&cnt, local);
        __syncthreads();
        if (t == 0) lens[b] = cnt;
    }
}

// V (B,H,S,64) -> V^T (B,H,64,S) with per-32-key permutation:
// position p = g*8+j  holds key = (j<4) ? 4g+j : 16+4g+(j-4)   (g=0..3, j=0..7)
__global__ __launch_bounds__(256) void vtrans_kernel(const short* __restrict__ V,
                                                     short* __restrict__ VT,
                                                     const int* __restrict__ lens) {
    __shared__ short t[64][65];
    int tid = threadIdx.x;
    int bh = blockIdx.y, s0 = blockIdx.x * 64;
    int b = bh >> 4;
    int kv_end = ((lens[b] + 63) >> 6) << 6;
    if (s0 >= kv_end) return;
    int rr = tid >> 2, c4 = (tid & 3) * 16;
    const short* vrow = V + ((size_t)bh * Sc + s0 + rr) * 64 + c4;
    *(bf16x8*)&t[rr][c4]     = *(const bf16x8*)(vrow);
    *(bf16x8*)&t[rr][c4 + 8] = *(const bf16x8*)(vrow + 8);
    __syncthreads();
    int q2 = tid & 3;
    int gidx = q2 >> 1, half = q2 & 1;
    int base = gidx * 32, off = half * 8;
    bf16x8 a, b2;
#pragma unroll
    for (int i = 0; i < 4; i++) {
        a[i]      = t[base + off + i][rr];
        a[4 + i]  = t[base + 16 + off + i][rr];
        b2[i]     = t[base + off + 4 + i][rr];
        b2[4 + i] = t[base + 16 + off + 4 + i][rr];
    }
    short* orow = VT + ((size_t)bh * 64 + rr) * Sc + s0 + base + half * 16;
    *(bf16x8*)(orow)     = a;
    *(bf16x8*)(orow + 8) = b2;
}

// ---------------- 128x128 bf16 MFMA GEMM: QKV projection (BK=32, r16-proven) --------
__global__ __launch_bounds__(256) void gemm_qkv_kernel(
    const short* __restrict__ A, const short* __restrict__ BT, const float* __restrict__ bias,
    short* __restrict__ Qp, short* __restrict__ Kp, short* __restrict__ Vp,
    const int* __restrict__ lens)
{
    __shared__ short As[128 * 32];
    __shared__ short Bs[128 * 32];
    int tid = threadIdx.x, lane = tid & 63, wave = tid >> 6;
    int l15 = lane & 15, lhi = lane >> 4;
    int bm = blockIdx.x, bn = blockIdx.y;

    if (bn >= 8) {                          // K or V columns: skip fully-masked row blocks
        int brow = bm >> 4;
        int s_lo = (bm & 15) * 128;
        int kv_end = ((lens[brow] + 63) >> 6) << 6;
        if (s_lo >= kv_end) return;
    }

    int wm = wave >> 1, wn = wave & 1;

    const f32x4 fzero = {0.f, 0.f, 0.f, 0.f};
    f32x4 acc[4][4];
#pragma unroll
    for (int i = 0; i < 4; i++)
#pragma unroll
        for (int j = 0; j < 4; j++) acc[i][j] = fzero;

    const char* Ab = (const char*)A;
    const char* Bb = (const char*)BT;

    for (int k0 = 0; k0 < 1024; k0 += 32) {
#pragma unroll
        for (int i = 0; i < 2; i++) {
            int o = wave * 2048 + i * 1024 + lane * 16;
            int row = o >> 6, cb = o & 63;
            gload16(Ab + ((size_t)(bm * 128 + row) * 1024 + k0) * 2 + cb,
                    (char*)As + wave * 2048 + i * 1024);
            gload16(Bb + ((size_t)(bn * 128 + row) * 1024 + k0) * 2 + cb,
                    (char*)Bs + wave * 2048 + i * 1024);
        }
        __syncthreads();
        bf16x8 af[4], bfv[4];
#pragma unroll
        for (int i = 0; i < 4; i++) {
            af[i]  = *(const bf16x8*)(As + (wm * 64 + i * 16 + l15) * 32 + lhi * 8);
            bfv[i] = *(const bf16x8*)(Bs + (wn * 64 + i * 16 + l15) * 32 + lhi * 8);
        }
#pragma unroll
        for (int i = 0; i < 4; i++)
#pragma unroll
            for (int j = 0; j < 4; j++)
                acc[i][j] = __builtin_amdgcn_mfma_f32_16x16x32_bf16(af[i], bfv[j], acc[i][j], 0, 0, 0);
        __syncthreads();
    }

#pragma unroll
    for (int i = 0; i < 4; i++)
#pragma unroll
        for (int j = 0; j < 4; j++) {
            int c = bn * 128 + wn * 64 + j * 16 + l15;
            float bc = bias[c];
            int rb = bm * 128 + wm * 64 + i * 16 + 4 * lhi;
#pragma unroll
            for (int reg = 0; reg < 4; reg++) {
                int r = rb + reg;
                float v = acc[i][j][reg] + bc;
                int which = c >> 10, cc = c & 1023, h = cc >> 6, d = cc & 63;
                int b = r >> 11, s = r & 2047;
                int bh = b * Hc + h;
                if (which == 0) v *= 0.18033688f;   // fold 1/8 * log2(e) into Q
                short sv = f2bf(v);
                size_t idx = ((size_t)bh * Sc + s) * 64 + d;
                if (which == 0)      Qp[idx] = sv;
                else if (which == 1) Kp[idx] = sv;
                else                 Vp[idx] = sv;
            }
        }
}

// ---------------- 128x64 bf16 MFMA GEMM: output projection (BK=32, r16-proven) ------
__global__ __launch_bounds__(256) void gemm_out_kernel(
    const short* __restrict__ A, const short* __restrict__ BT, const float* __restrict__ bias,
    float* __restrict__ outF)
{
    __shared__ short As[128 * 32];
    __shared__ short Bs[64 * 32];
    int tid = threadIdx.x, lane = tid & 63, wave = tid >> 6;
    int l15 = lane & 15, lhi = lane >> 4;
    int bm = blockIdx.x, bn = blockIdx.y;

    const f32x4 fzero = {0.f, 0.f, 0.f, 0.f};
    f32x4 acc[2][4];
#pragma unroll
    for (int i = 0; i < 2; i++)
#pragma unroll
        for (int j = 0; j < 4; j++) acc[i][j] = fzero;

    const char* Ab = (const char*)A;
    const char* Bb = (const char*)BT;

    for (int k0 = 0; k0 < 1024; k0 += 32) {
#pragma unroll
        for (int i = 0; i < 2; i++) {
            int o = wave * 2048 + i * 1024 + lane * 16;
            int row = o >> 6, cb = o & 63;
            gload16(Ab + ((size_t)(bm * 128 + row) * 1024 + k0) * 2 + cb,
                    (char*)As + wave * 2048 + i * 1024);
        }
        {
            int o = wave * 1024 + lane * 16;
            int row = o >> 6, cb = o & 63;
            gload16(Bb + ((size_t)(bn * 64 + row) * 1024 + k0) * 2 + cb,
                    (char*)Bs + wave * 1024);
        }
        __syncthreads();
        bf16x8 af[2], bfv[4];
#pragma unroll
        for (int i = 0; i < 2; i++)
            af[i] = *(const bf16x8*)(As + (wave * 32 + i * 16 + l15) * 32 + lhi * 8);
#pragma unroll
        for (int j = 0; j < 4; j++)
            bfv[j] = *(const bf16x8*)(Bs + (j * 16 + l15) * 32 + lhi * 8);
#pragma unroll
        for (int i = 0; i < 2; i++)
#pragma unroll
            for (int j = 0; j < 4; j++)
                acc[i][j] = __builtin_amdgcn_mfma_f32_16x16x32_bf16(af[i], bfv[j], acc[i][j], 0, 0, 0);
        __syncthreads();
    }

#pragma unroll
    for (int i = 0; i < 2; i++)
#pragma unroll
        for (int j = 0; j < 4; j++) {
            int c = bn * 64 + j * 16 + l15;
            float bc = bias[c];
            int rb = bm * 128 + wave * 32 + i * 16 + 4 * lhi;
#pragma unroll
            for (int reg = 0; reg < 4; reg++)
                outF[(size_t)(rb + reg) * Dc + c] = acc[i][j][reg] + bc;
        }
}

// ------- flash attention: 16x16x32 swapped-operand + l-via-MFMA (r17-proven) --------
// 4-wave blocks (64 q-rows), grid 1024, batch-balanced bijective XCD swizzle.
// QK^T = mfma(K, Q) -> q = lane&15 lane-local. PV = mfma(V^T, P) with 32-key
// pi-permuted V^T. l accumulated by mfma(ones, P) (permutation-invariant sum over
// keys): no VALU tree-sum, no epilogue shuffles. Conflict-free LDS (measured 0).
__global__ __launch_bounds__(256) void attn_kernel(
    const short* __restrict__ Qp, const short* __restrict__ Kp, const short* __restrict__ VTp,
    const int* __restrict__ lens, short* __restrict__ Xout)
{
    int tid = threadIdx.x, lane = tid & 63, wave = tid >> 6;   // wave 0..3
    int l15 = lane & 15, g4 = lane >> 4;                       // g4 0..3

    int orig = blockIdx.x;                  // 1024 blocks, 1024 % 8 == 0 -> bijective
    int xcd = orig & 7, idx = orig >> 3;
    int j = idx & 3, bx = idx >> 2;
    int bh = ((j >> 1) << 4) + xcd * 2 + (j & 1);
    int b = bh >> 4, h = bh & 15;
    int q0 = bx * 64 + wave * 16;

    __shared__ short Kt[2][64 * 64];
    __shared__ short Vt[2][64 * 64];

    const short* Qb  = Qp + (size_t)bh * Sc * 64;
    const char*  Kb  = (const char*)(Kp + (size_t)bh * Sc * 64);
    const char*  VTb = (const char*)(VTp + (size_t)bh * 64 * Sc);

    bf16x8 qf0 = *(const bf16x8*)(Qb + (size_t)(q0 + l15) * 64 + g4 * 8);
    bf16x8 qf1 = *(const bf16x8*)(Qb + (size_t)(q0 + l15) * 64 + 32 + g4 * 8);

    bf16x8 onesv;
#pragma unroll
    for (int i = 0; i < 8; i++) onesv[i] = (short)0x3F80;   // bf16 1.0

    const f32x4 FZ = {0.f, 0.f, 0.f, 0.f};
    f32x4 xacc[4], lacc = FZ;
#pragma unroll
    for (int dt = 0; dt < 4; dt++) xacc[dt] = FZ;

    int len = lens[b];
    int nt = (len + 63) >> 6;
    int rsw = (l15 & 7) << 4;
    int g16 = g4 * 16;

#define STAGE(bufi, kt_)                                                              \
    {                                                                                 \
        int k0_ = (kt_) * 64;                                                         \
        _Pragma("unroll")                                                             \
        for (int i = 0; i < 2; i++) {                                                 \
            int o = i * 4096 + tid * 16;                                              \
            int row = o >> 7, cb = o & 127;                                           \
            int scb = cb ^ ((row & 7) << 4);                                          \
            gload16(Kb + (size_t)(k0_ + row) * 128 + scb,                             \
                    (char*)&Kt[bufi][0] + o);                                         \
            gload16(VTb + (size_t)row * (Sc * 2) + (size_t)k0_ * 2 + scb,             \
                    (char*)&Vt[bufi][0] + o);                                         \
        }                                                                             \
    }

#define DOTILE(BUFI, KT)                                                              \
    {                                                                                 \
        const char* Kc = (const char*)&Kt[BUFI][0];                                   \
        const char* Vc = (const char*)&Vt[BUFI][0];                                   \
        f32x4 s[4];                                                                   \
        __builtin_amdgcn_s_setprio(1);                                                \
        _Pragma("unroll")                                                             \
        for (int k16 = 0; k16 < 4; k16++) {                                           \
            const char* kr = Kc + (k16 * 16 + l15) * 128;                             \
            bf16x8 kf0 = *(const bf16x8*)(kr + (g16 ^ rsw));                          \
            bf16x8 kf1 = *(const bf16x8*)(kr + ((64 + g16) ^ rsw));                   \
            s[k16] = __builtin_amdgcn_mfma_f32_16x16x32_bf16(kf0, qf0, FZ, 0, 0, 0);  \
            s[k16] = __builtin_amdgcn_mfma_f32_16x16x32_bf16(kf1, qf1, s[k16], 0, 0, 0);\
        }                                                                             \
        __builtin_amdgcn_s_setprio(0);                                                \
        if ((KT) == nt - 1) {                                                         \
            int rem = len - (KT) * 64;                                                \
            if (rem < 64) {                                                           \
                _Pragma("unroll")                                                     \
                for (int k16 = 0; k16 < 4; k16++)                                     \
                    _Pragma("unroll")                                                 \
                    for (int r = 0; r < 4; r++) {                                     \
                        int key0 = k16 * 16 + 4 * g4 + r;                             \
                        if (key0 >= rem) s[k16][r] = -3.0e38f;                        \
                    }                                                                 \
            }                                                                         \
        }                                                                             \
        _Pragma("unroll")                                                             \
        for (int k16 = 0; k16 < 4; k16++)                                             \
            _Pragma("unroll")                                                         \
            for (int r = 0; r < 4; r++) s[k16][r] = vexp2(s[k16][r]);                 \
        I4BF p0, p1;                                                                  \
        p0.i[0] = cvtpk(s[0][0], s[0][1]); p0.i[1] = cvtpk(s[0][2], s[0][3]);         \
        p0.i[2] = cvtpk(s[1][0], s[1][1]); p0.i[3] = cvtpk(s[1][2], s[1][3]);         \
        p1.i[0] = cvtpk(s[2][0], s[2][1]); p1.i[1] = cvtpk(s[2][2], s[2][3]);         \
        p1.i[2] = cvtpk(s[3][0], s[3][1]); p1.i[3] = cvtpk(s[3][2], s[3][3]);         \
        __builtin_amdgcn_s_setprio(1);                                                \
        lacc = __builtin_amdgcn_mfma_f32_16x16x32_bf16(onesv, p0.v, lacc, 0, 0, 0);   \
        lacc = __builtin_amdgcn_mfma_f32_16x16x32_bf16(onesv, p1.v, lacc, 0, 0, 0);   \
        _Pragma("unroll")                                                             \
        for (int dt = 0; dt < 4; dt++) {                                              \
            const char* vr = Vc + (dt * 16 + l15) * 128;                              \
            bf16x8 v0 = *(const bf16x8*)(vr + (g16 ^ rsw));                           \
            bf16x8 v1 = *(const bf16x8*)(vr + ((64 + g16) ^ rsw));                    \
            xacc[dt] = __builtin_amdgcn_mfma_f32_16x16x32_bf16(v0, p0.v, xacc[dt], 0, 0, 0);\
            xacc[dt] = __builtin_amdgcn_mfma_f32_16x16x32_bf16(v1, p1.v, xacc[dt], 0, 0, 0);\
        }                                                                             \
        __builtin_amdgcn_s_setprio(0);                                                \
    }

    STAGE(0, 0);
    __syncthreads();

    int kt = 0;
    while (kt + 2 <= nt) {
        if (kt + 1 < nt) STAGE(1, kt + 1);
        DOTILE(0, kt);
        __syncthreads();
        if (kt + 2 < nt) STAGE(0, kt + 2);
        DOTILE(1, kt + 1);
        __syncthreads();
        kt += 2;
    }
    if (kt < nt) DOTILE(0, kt);

    // epilogue: every lane already holds l for q=l15 in lacc (all rows identical)
    float rl = 1.0f / lacc[0];
    short* orow = Xout + (size_t)(b * Sc + q0 + l15) * Dc + h * 64;
#pragma unroll
    for (int dt = 0; dt < 4; dt++) {
        short4 o;
        o.x = f2bf(xacc[dt][0] * rl);
        o.y = f2bf(xacc[dt][1] * rl);
        o.z = f2bf(xacc[dt][2] * rl);
        o.w = f2bf(xacc[dt][3] * rl);
        *(short4*)(orow + dt * 16 + 4 * g4) = o;
    }
}

// ---------------- launch ----------------

extern "C" void kernel_launch(void* const* d_in, const int* in_sizes, int n_in,
                              void* d_out, int out_size, void* d_ws, size_t ws_size,
                              hipStream_t stream) {
    const float* batch = (const float*)d_in[0];
    const unsigned char* mask = (const unsigned char*)d_in[1];
    const float* Wq = (const float*)d_in[2];
    const float* bq = (const float*)d_in[3];
    const float* Wk = (const float*)d_in[4];
    const float* bk = (const float*)d_in[5];
    const float* Wv = (const float*)d_in[6];
    const float* bv = (const float*)d_in[7];
    const float* Wo = (const float*)d_in[8];
    const float* bo = (const float*)d_in[9];

    char* ws = (char*)d_ws;
    short* XB    = (short*)(ws + OFF_XB);
    short* WQKVT = (short*)(ws + OFF_WQKVT);
    short* WOT   = (short*)(ws + OFF_WOT);
    short* Qb    = (short*)(ws + OFF_Q);
    short* Kb    = (short*)(ws + OFF_K);
    short* VTb   = (short*)(ws + OFF_VT);
    short* XAb   = (short*)(ws + OFF_XA);
    float* BIASC = (float*)(ws + OFF_BIASC);
    int*   LENS  = (int*)(ws + OFF_LENS);
    short* Vscr  = (short*)d_out;   // V (B,H,S,64) scratch in d_out (overwritten by gemm_out)

    prep_all_kernel<<<8195, 256, 0, stream>>>(batch, Wq, Wk, Wv, Wo, bq, bk, bv, mask,
                                              XB, WQKVT, WOT, BIASC, LENS);
    gemm_qkv_kernel<<<dim3(32, 24), 256, 0, stream>>>(XB, WQKVT, BIASC, Qb, Kb, Vscr, LENS);
    vtrans_kernel<<<dim3(32, 32), 256, 0, stream>>>(Vscr, VTb, LENS);
    attn_kernel<<<1024, 256, 0, stream>>>(Qb, Kb, VTb, LENS, XAb);
    gemm_out_kernel<<<dim3(32, 16), 256, 0, stream>>>(XAb, WOT, bo, (float*)d_out);
}

// Round 19
// 117.032 us; speedup vs baseline: 1.0534x; 1.0117x over previous
//
#include <hip/hip_runtime.h>
#include <hip/hip_bf16.h>

#define DEV __device__ __forceinline__

typedef short bf16x8 __attribute__((ext_vector_type(8)));
typedef float f32x4  __attribute__((ext_vector_type(4)));

#define Bc 2
#define Sc 2048
#define Dc 1024
#define Hc 16
// DEPTH = 64, M = B*S = 4096

// ---- workspace layout (bytes) ----
#define OFF_XB    0u           // batch bf16        [4096][1024]   8388608
#define OFF_WQKVT 8388608u     // Wqkv^T bf16       [3072][1024]   6291456
#define OFF_WOT   14680064u    // Wo^T bf16         [1024][1024]   2097152
#define OFF_Q     16777216u    // Q bf16 (B,H,S,64), pre-scaled    8388608
#define OFF_K     25165824u    // K bf16 (B,H,S,64)                8388608
#define OFF_VT    33554432u    // V^T bf16 (B,H,64,S) KEY-PERMUTED 8388608
#define OFF_XA    41943040u    // attn out bf16 [4096][1024]       8388608
#define OFF_BIASC 50331648u    // f32 [3072]                         12288
#define OFF_LENS  50343936u    // int [B]
// V (B,H,S,64) bf16 scratch lives in d_out[0..8MB) — rewritten every call,
// consumed by vtrans, then fully overwritten by gemm_out (deterministic).

DEV short f2bf(float f) {
    __hip_bfloat16 h = __float2bfloat16(f);
    union { __hip_bfloat16 h; short s; } u; u.h = h; return u.s;
}

DEV int cvtpk(float lo, float hi_) {
    int r;
    asm("v_cvt_pk_bf16_f32 %0, %1, %2" : "=v"(r) : "v"(lo), "v"(hi_));
    return r;
}

DEV float vexp2(float x) {
    float r;
    asm("v_exp_f32 %0, %1" : "=v"(r) : "v"(x));   // hardware 2^x, ~1 ULP
    return r;
}

DEV void gload16(const void* g, void* l) {
    __builtin_amdgcn_global_load_lds((const __attribute__((address_space(1))) void*)g,
                                     (__attribute__((address_space(3))) void*)l, 16, 0, 0);
}

union I4BF { int i[4]; bf16x8 v; };

// ---------------- fused prep: cast + 4x weight transpose + bias/mask ----------------
__global__ __launch_bounds__(256) void prep_all_kernel(
    const float* __restrict__ batch,
    const float* __restrict__ Wq, const float* __restrict__ Wk,
    const float* __restrict__ Wv, const float* __restrict__ Wo,
    const float* __restrict__ bq, const float* __restrict__ bk, const float* __restrict__ bv,
    const unsigned char* __restrict__ mask,
    short* __restrict__ XB, short* __restrict__ WQKVT, short* __restrict__ WOT,
    float* __restrict__ biasc, int* __restrict__ lens)
{
    __shared__ float tsm[32][33];
    __shared__ int cnt;
    int blk = blockIdx.x, t = threadIdx.x;

    if (blk < 4096) {                       // ---- cast batch f32 -> bf16 (float4/lane)
        int i = blk * 256 + t;
        float4 v = ((const float4*)batch)[i];
        short4 o;
        o.x = f2bf(v.x); o.y = f2bf(v.y); o.z = f2bf(v.z); o.w = f2bf(v.w);
        ((short4*)XB)[i] = o;
        return;
    }
    if (blk < 8192) {                       // ---- weight transpose-cast (4 x 1024 tiles)
        int w = blk - 4096, z = w >> 10, tile = w & 1023;
        const float* src; short* dst;
        if (z == 0)      { src = Wq; dst = WQKVT; }
        else if (z == 1) { src = Wk; dst = WQKVT + 1024 * 1024; }
        else if (z == 2) { src = Wv; dst = WQKVT + 2 * 1024 * 1024; }
        else             { src = Wo; dst = WOT; }
        int tx = t & 31, ty = t >> 5;       // 32 x 8
        int r0 = (tile >> 5) * 32, c0 = (tile & 31) * 32;
#pragma unroll
        for (int i = 0; i < 4; i++)
            tsm[ty + i * 8][tx] = src[(size_t)(r0 + ty + i * 8) * Dc + c0 + tx];
        __syncthreads();
#pragma unroll
        for (int i = 0; i < 4; i++)
            dst[(size_t)(c0 + ty + i * 8) * Dc + r0 + tx] = f2bf(tsm[tx][ty + i * 8]);
        return;
    }
    if (blk == 8192) {                      // ---- bias concat
        for (int i = t; i < Dc; i += 256) {
            biasc[i] = bq[i]; biasc[Dc + i] = bk[i]; biasc[2 * Dc + i] = bv[i];
        }
        return;
    }
    {                                       // ---- mask lengths (blocks 8193, 8194)
        int b = blk - 8193;
        bool is_i32 = (mask[1] == 0);
        if (t == 0) cnt = 0;
        __syncthreads();
        int local = 0;
        for (int s = t; s < Sc; s += 256) {
            bool v = is_i32 ? (((const int*)mask)[b * Sc + s] != 0) : (mask[b * Sc + s] != 0);
            local += v ? 1 : 0;
        }
        atomicAdd(&cnt, local);
        __syncthreads();
        if (t == 0) lens[b] = cnt;
    }
}

// V (B,H,S,64) -> V^T (B,H,64,S) with per-32-key permutation:
// position p = g*8+j  holds key = (j<4) ? 4g+j : 16+4g+(j-4)   (g=0..3, j=0..7)
__global__ __launch_bounds__(256) void vtrans_kernel(const short* __restrict__ V,
                                                     short* __restrict__ VT,
                                                     const int* __restrict__ lens) {
    __shared__ short t[64][65];
    int tid = threadIdx.x;
    int bh = blockIdx.y, s0 = blockIdx.x * 64;
    int b = bh >> 4;
    int kv_end = ((lens[b] + 63) >> 6) << 6;
    if (s0 >= kv_end) return;
    int rr = tid >> 2, c4 = (tid & 3) * 16;
    const short* vrow = V + ((size_t)bh * Sc + s0 + rr) * 64 + c4;
    *(bf16x8*)&t[rr][c4]     = *(const bf16x8*)(vrow);
    *(bf16x8*)&t[rr][c4 + 8] = *(const bf16x8*)(vrow + 8);
    __syncthreads();
    int q2 = tid & 3;
    int gidx = q2 >> 1, half = q2 & 1;
    int base = gidx * 32, off = half * 8;
    bf16x8 a, b2;
#pragma unroll
    for (int i = 0; i < 4; i++) {
        a[i]      = t[base + off + i][rr];
        a[4 + i]  = t[base + 16 + off + i][rr];
        b2[i]     = t[base + off + 4 + i][rr];
        b2[4 + i] = t[base + 16 + off + 4 + i][rr];
    }
    short* orow = VT + ((size_t)bh * 64 + rr) * Sc + s0 + base + half * 16;
    *(bf16x8*)(orow)     = a;
    *(bf16x8*)(orow + 8) = b2;
}

// ---------------- 128x128 bf16 MFMA GEMM: QKV projection (BK=32) --------------------
// 1D grid 768 with bijective XCD-chunk swizzle (T1): XCD c owns bm in [4c,4c+4) for
// ALL 24 bn -> per-XCD A footprint 1MB (L2-resident across the whole bn sweep),
// B panels streamed once. 768 % 8 == 0 -> bijective.
__global__ __launch_bounds__(256) void gemm_qkv_kernel(
    const short* __restrict__ A, const short* __restrict__ BT, const float* __restrict__ bias,
    short* __restrict__ Qp, short* __restrict__ Kp, short* __restrict__ Vp,
    const int* __restrict__ lens)
{
    __shared__ short As[128 * 32];
    __shared__ short Bs[128 * 32];
    int tid = threadIdx.x, lane = tid & 63, wave = tid >> 6;
    int l15 = lane & 15, lhi = lane >> 4;

    int orig = blockIdx.x;                  // 768 blocks
    int xcd = orig & 7, idx = orig >> 3;    // idx 0..95
    int bm = xcd * 4 + (idx & 3);           // 4 bm-rows per XCD
    int bn = idx >> 2;                      // bn sweeps 0..23 within the XCD

    if (bn >= 8) {                          // K or V columns: skip fully-masked row blocks
        int brow = bm >> 4;
        int s_lo = (bm & 15) * 128;
        int kv_end = ((lens[brow] + 63) >> 6) << 6;
        if (s_lo >= kv_end) return;
    }

    int wm = wave >> 1, wn = wave & 1;

    const f32x4 fzero = {0.f, 0.f, 0.f, 0.f};
    f32x4 acc[4][4];
#pragma unroll
    for (int i = 0; i < 4; i++)
#pragma unroll
        for (int j = 0; j < 4; j++) acc[i][j] = fzero;

    const char* Ab = (const char*)A;
    const char* Bb = (const char*)BT;

    for (int k0 = 0; k0 < 1024; k0 += 32) {
#pragma unroll
        for (int i = 0; i < 2; i++) {
            int o = wave * 2048 + i * 1024 + lane * 16;
            int row = o >> 6, cb = o & 63;
            gload16(Ab + ((size_t)(bm * 128 + row) * 1024 + k0) * 2 + cb,
                    (char*)As + wave * 2048 + i * 1024);
            gload16(Bb + ((size_t)(bn * 128 + row) * 1024 + k0) * 2 + cb,
                    (char*)Bs + wave * 2048 + i * 1024);
        }
        __syncthreads();
        bf16x8 af[4], bfv[4];
#pragma unroll
        for (int i = 0; i < 4; i++) {
            af[i]  = *(const bf16x8*)(As + (wm * 64 + i * 16 + l15) * 32 + lhi * 8);
            bfv[i] = *(const bf16x8*)(Bs + (wn * 64 + i * 16 + l15) * 32 + lhi * 8);
        }
#pragma unroll
        for (int i = 0; i < 4; i++)
#pragma unroll
            for (int j = 0; j < 4; j++)
                acc[i][j] = __builtin_amdgcn_mfma_f32_16x16x32_bf16(af[i], bfv[j], acc[i][j], 0, 0, 0);
        __syncthreads();
    }

#pragma unroll
    for (int i = 0; i < 4; i++)
#pragma unroll
        for (int j = 0; j < 4; j++) {
            int c = bn * 128 + wn * 64 + j * 16 + l15;
            float bc = bias[c];
            int rb = bm * 128 + wm * 64 + i * 16 + 4 * lhi;
#pragma unroll
            for (int reg = 0; reg < 4; reg++) {
                int r = rb + reg;
                float v = acc[i][j][reg] + bc;
                int which = c >> 10, cc = c & 1023, h = cc >> 6, d = cc & 63;
                int b = r >> 11, s = r & 2047;
                int bh = b * Hc + h;
                if (which == 0) v *= 0.18033688f;   // fold 1/8 * log2(e) into Q
                short sv = f2bf(v);
                size_t idx2 = ((size_t)bh * Sc + s) * 64 + d;
                if (which == 0)      Qp[idx2] = sv;
                else if (which == 1) Kp[idx2] = sv;
                else                 Vp[idx2] = sv;
            }
        }
}

// ---------------- 128x64 bf16 MFMA GEMM: output projection (BK=32) ------------------
// 1D grid 512 with the same bijective XCD-chunk swizzle: XCD c owns bm in [4c,4c+4)
// for all 16 bn (A-chunk 1MB L2-resident). 512 % 8 == 0 -> bijective.
__global__ __launch_bounds__(256) void gemm_out_kernel(
    const short* __restrict__ A, const short* __restrict__ BT, const float* __restrict__ bias,
    float* __restrict__ outF)
{
    __shared__ short As[128 * 32];
    __shared__ short Bs[64 * 32];
    int tid = threadIdx.x, lane = tid & 63, wave = tid >> 6;
    int l15 = lane & 15, lhi = lane >> 4;

    int orig = blockIdx.x;                  // 512 blocks
    int xcd = orig & 7, idx = orig >> 3;    // idx 0..63
    int bm = xcd * 4 + (idx & 3);
    int bn = idx >> 2;                      // 0..15

    const f32x4 fzero = {0.f, 0.f, 0.f, 0.f};
    f32x4 acc[2][4];
#pragma unroll
    for (int i = 0; i < 2; i++)
#pragma unroll
        for (int j = 0; j < 4; j++) acc[i][j] = fzero;

    const char* Ab = (const char*)A;
    const char* Bb = (const char*)BT;

    for (int k0 = 0; k0 < 1024; k0 += 32) {
#pragma unroll
        for (int i = 0; i < 2; i++) {
            int o = wave * 2048 + i * 1024 + lane * 16;
            int row = o >> 6, cb = o & 63;
            gload16(Ab + ((size_t)(bm * 128 + row) * 1024 + k0) * 2 + cb,
                    (char*)As + wave * 2048 + i * 1024);
        }
        {
            int o = wave * 1024 + lane * 16;
            int row = o >> 6, cb = o & 63;
            gload16(Bb + ((size_t)(bn * 64 + row) * 1024 + k0) * 2 + cb,
                    (char*)Bs + wave * 1024);
        }
        __syncthreads();
        bf16x8 af[2], bfv[4];
#pragma unroll
        for (int i = 0; i < 2; i++)
            af[i] = *(const bf16x8*)(As + (wave * 32 + i * 16 + l15) * 32 + lhi * 8);
#pragma unroll
        for (int j = 0; j < 4; j++)
            bfv[j] = *(const bf16x8*)(Bs + (j * 16 + l15) * 32 + lhi * 8);
#pragma unroll
        for (int i = 0; i < 2; i++)
#pragma unroll
            for (int j = 0; j < 4; j++)
                acc[i][j] = __builtin_amdgcn_mfma_f32_16x16x32_bf16(af[i], bfv[j], acc[i][j], 0, 0, 0);
        __syncthreads();
    }

#pragma unroll
    for (int i = 0; i < 2; i++)
#pragma unroll
        for (int j = 0; j < 4; j++) {
            int c = bn * 64 + j * 16 + l15;
            float bc = bias[c];
            int rb = bm * 128 + wave * 32 + i * 16 + 4 * lhi;
#pragma unroll
            for (int reg = 0; reg < 4; reg++)
                outF[(size_t)(rb + reg) * Dc + c] = acc[i][j][reg] + bc;
        }
}

// ------- flash attention: 16x16x32 swapped-operand + l-via-MFMA (r17/r18-proven) ----
// 4-wave blocks (64 q-rows), grid 1024, batch-balanced bijective XCD swizzle.
// QK^T = mfma(K, Q) -> q = lane&15 lane-local. PV = mfma(V^T, P) with 32-key
// pi-permuted V^T. l accumulated by mfma(ones, P) (permutation-invariant sum over
// keys): no VALU tree-sum, no epilogue shuffles. Conflict-free LDS (measured 0).
__global__ __launch_bounds__(256) void attn_kernel(
    const short* __restrict__ Qp, const short* __restrict__ Kp, const short* __restrict__ VTp,
    const int* __restrict__ lens, short* __restrict__ Xout)
{
    int tid = threadIdx.x, lane = tid & 63, wave = tid >> 6;   // wave 0..3
    int l15 = lane & 15, g4 = lane >> 4;                       // g4 0..3

    int orig = blockIdx.x;                  // 1024 blocks, 1024 % 8 == 0 -> bijective
    int xcd = orig & 7, idx = orig >> 3;
    int j = idx & 3, bx = idx >> 2;
    int bh = ((j >> 1) << 4) + xcd * 2 + (j & 1);
    int b = bh >> 4, h = bh & 15;
    int q0 = bx * 64 + wave * 16;

    __shared__ short Kt[2][64 * 64];
    __shared__ short Vt[2][64 * 64];

    const short* Qb  = Qp + (size_t)bh * Sc * 64;
    const char*  Kb  = (const char*)(Kp + (size_t)bh * Sc * 64);
    const char*  VTb = (const char*)(VTp + (size_t)bh * 64 * Sc);

    bf16x8 qf0 = *(const bf16x8*)(Qb + (size_t)(q0 + l15) * 64 + g4 * 8);
    bf16x8 qf1 = *(const bf16x8*)(Qb + (size_t)(q0 + l15) * 64 + 32 + g4 * 8);

    bf16x8 onesv;
#pragma unroll
    for (int i = 0; i < 8; i++) onesv[i] = (short)0x3F80;   // bf16 1.0

    const f32x4 FZ = {0.f, 0.f, 0.f, 0.f};
    f32x4 xacc[4], lacc = FZ;
#pragma unroll
    for (int dt = 0; dt < 4; dt++) xacc[dt] = FZ;

    int len = lens[b];
    int nt = (len + 63) >> 6;
    int rsw = (l15 & 7) << 4;
    int g16 = g4 * 16;

#define STAGE(bufi, kt_)                                                              \
    {                                                                                 \
        int k0_ = (kt_) * 64;                                                         \
        _Pragma("unroll")                                                             \
        for (int i = 0; i < 2; i++) {                                                 \
            int o = i * 4096 + tid * 16;                                              \
            int row = o >> 7, cb = o & 127;                                           \
            int scb = cb ^ ((row & 7) << 4);                                          \
            gload16(Kb + (size_t)(k0_ + row) * 128 + scb,                             \
                    (char*)&Kt[bufi][0] + o);                                         \
            gload16(VTb + (size_t)row * (Sc * 2) + (size_t)k0_ * 2 + scb,             \
                    (char*)&Vt[bufi][0] + o);                                         \
        }                                                                             \
    }

#define DOTILE(BUFI, KT)                                                              \
    {                                                                                 \
        const char* Kc = (const char*)&Kt[BUFI][0];                                   \
        const char* Vc = (const char*)&Vt[BUFI][0];                                   \
        f32x4 s[4];                                                                   \
        __builtin_amdgcn_s_setprio(1);                                                \
        _Pragma("unroll")                                                             \
        for (int k16 = 0; k16 < 4; k16++) {                                           \
            const char* kr = Kc + (k16 * 16 + l15) * 128;                             \
            bf16x8 kf0 = *(const bf16x8*)(kr + (g16 ^ rsw));                          \
            bf16x8 kf1 = *(const bf16x8*)(kr + ((64 + g16) ^ rsw));                   \
            s[k16] = __builtin_amdgcn_mfma_f32_16x16x32_bf16(kf0, qf0, FZ, 0, 0, 0);  \
            s[k16] = __builtin_amdgcn_mfma_f32_16x16x32_bf16(kf1, qf1, s[k16], 0, 0, 0);\
        }                                                                             \
        __builtin_amdgcn_s_setprio(0);                                                \
        if ((KT) == nt - 1) {                                                         \
            int rem = len - (KT) * 64;                                                \
            if (rem < 64) {                                                           \
                _Pragma("unroll")                                                     \
                for (int k16 = 0; k16 < 4; k16++)                                     \
                    _Pragma("unroll")                                                 \
                    for (int r = 0; r < 4; r++) {                                     \
                        int key0 = k16 * 16 + 4 * g4 + r;                             \
                        if (key0 >= rem) s[k16][r] = -3.0e38f;                        \
                    }                                                                 \
            }                                                                         \
        }                                                                             \
        _Pragma("unroll")                                                             \
        for (int k16 = 0; k16 < 4; k16++)                                             \
            _Pragma("unroll")                                                         \
            for (int r = 0; r < 4; r++) s[k16][r] = vexp2(s[k16][r]);                 \
        I4BF p0, p1;                                                                  \
        p0.i[0] = cvtpk(s[0][0], s[0][1]); p0.i[1] = cvtpk(s[0][2], s[0][3]);         \
        p0.i[2] = cvtpk(s[1][0], s[1][1]); p0.i[3] = cvtpk(s[1][2], s[1][3]);         \
        p1.i[0] = cvtpk(s[2][0], s[2][1]); p1.i[1] = cvtpk(s[2][2], s[2][3]);         \
        p1.i[2] = cvtpk(s[3][0], s[3][1]); p1.i[3] = cvtpk(s[3][2], s[3][3]);         \
        __builtin_amdgcn_s_setprio(1);                                                \
        lacc = __builtin_amdgcn_mfma_f32_16x16x32_bf16(onesv, p0.v, lacc, 0, 0, 0);   \
        lacc = __builtin_amdgcn_mfma_f32_16x16x32_bf16(onesv, p1.v, lacc, 0, 0, 0);   \
        _Pragma("unroll")                                                             \
        for (int dt = 0; dt < 4; dt++) {                                              \
            const char* vr = Vc + (dt * 16 + l15) * 128;                              \
            bf16x8 v0 = *(const bf16x8*)(vr + (g16 ^ rsw));                           \
            bf16x8 v1 = *(const bf16x8*)(vr + ((64 + g16) ^ rsw));                    \
            xacc[dt] = __builtin_amdgcn_mfma_f32_16x16x32_bf16(v0, p0.v, xacc[dt], 0, 0, 0);\
            xacc[dt] = __builtin_amdgcn_mfma_f32_16x16x32_bf16(v1, p1.v, xacc[dt], 0, 0, 0);\
        }                                                                             \
        __builtin_amdgcn_s_setprio(0);                                                \
    }

    STAGE(0, 0);
    __syncthreads();

    int kt = 0;
    while (kt + 2 <= nt) {
        if (kt + 1 < nt) STAGE(1, kt + 1);
        DOTILE(0, kt);
        __syncthreads();
        if (kt + 2 < nt) STAGE(0, kt + 2);
        DOTILE(1, kt + 1);
        __syncthreads();
        kt += 2;
    }
    if (kt < nt) DOTILE(0, kt);

    // epilogue: every lane already holds l for q=l15 in lacc (all rows identical)
    float rl = 1.0f / lacc[0];
    short* orow = Xout + (size_t)(b * Sc + q0 + l15) * Dc + h * 64;
#pragma unroll
    for (int dt = 0; dt < 4; dt++) {
        short4 o;
        o.x = f2bf(xacc[dt][0] * rl);
        o.y = f2bf(xacc[dt][1] * rl);
        o.z = f2bf(xacc[dt][2] * rl);
        o.w = f2bf(xacc[dt][3] * rl);
        *(short4*)(orow + dt * 16 + 4 * g4) = o;
    }
}

// ---------------- launch ----------------

extern "C" void kernel_launch(void* const* d_in, const int* in_sizes, int n_in,
                              void* d_out, int out_size, void* d_ws, size_t ws_size,
                              hipStream_t stream) {
    const float* batch = (const float*)d_in[0];
    const unsigned char* mask = (const unsigned char*)d_in[1];
    const float* Wq = (const float*)d_in[2];
    const float* bq = (const float*)d_in[3];
    const float* Wk = (const float*)d_in[4];
    const float* bk = (const float*)d_in[5];
    const float* Wv = (const float*)d_in[6];
    const float* bv = (const float*)d_in[7];
    const float* Wo = (const float*)d_in[8];
    const float* bo = (const float*)d_in[9];

    char* ws = (char*)d_ws;
    short* XB    = (short*)(ws + OFF_XB);
    short* WQKVT = (short*)(ws + OFF_WQKVT);
    short* WOT   = (short*)(ws + OFF_WOT);
    short* Qb    = (short*)(ws + OFF_Q);
    short* Kb    = (short*)(ws + OFF_K);
    short* VTb   = (short*)(ws + OFF_VT);
    short* XAb   = (short*)(ws + OFF_XA);
    float* BIASC = (float*)(ws + OFF_BIASC);
    int*   LENS  = (int*)(ws + OFF_LENS);
    short* Vscr  = (short*)d_out;   // V (B,H,S,64) scratch in d_out (overwritten by gemm_out)

    prep_all_kernel<<<8195, 256, 0, stream>>>(batch, Wq, Wk, Wv, Wo, bq, bk, bv, mask,
                                              XB, WQKVT, WOT, BIASC, LENS);
    gemm_qkv_kernel<<<768, 256, 0, stream>>>(XB, WQKVT, BIASC, Qb, Kb, Vscr, LENS);
    vtrans_kernel<<<dim3(32, 32), 256, 0, stream>>>(Vscr, VTb, LENS);
    attn_kernel<<<1024, 256, 0, stream>>>(Qb, Kb, VTb, LENS, XAb);
    gemm_out_kernel<<<512, 256, 0, stream>>>(XAb, WOT, bo, (float*)d_out);
}